// Round 5
// baseline (12398.244 us; speedup 1.0000x reference)
//
#include <hip/hip_runtime.h>
#include <math.h>

typedef unsigned short u16;
typedef unsigned int   u32;
typedef unsigned long long u64;
typedef __attribute__((ext_vector_type(8))) short short8;
typedef __attribute__((ext_vector_type(4))) float f32x4;
typedef __attribute__((ext_vector_type(4))) unsigned int u32x4;

__device__ __forceinline__ float bf2f(u16 v) { return __uint_as_float(((u32)v) << 16); }
__device__ __forceinline__ u16 f2bf(float f) {
    u32 u = __float_as_uint(f);
    u32 r = (u + 0x7fffu + ((u >> 16) & 1u)) >> 16;
    return (u16)r;
}
__device__ __forceinline__ u32 pk2(float a, float b) {
    return ((u32)f2bf(a)) | (((u32)f2bf(b)) << 16);
}
__device__ __forceinline__ float sigm(float x) { return 1.f / (1.f + __expf(-x)); }
__device__ __forceinline__ f32x4 mfma16(short8 a, short8 b, f32x4 c) {
    return __builtin_amdgcn_mfma_f32_16x16x32_bf16(a, b, c, 0, 0, 0);
}
__device__ __forceinline__ short8 ld8bf(const float* p) {
    short8 r;
#pragma unroll
    for (int j = 0; j < 8; ++j) r[j] = (short)f2bf(p[j]);
    return r;
}
// 16B cache-bypassing load (straight from the IF$ coherence point).
__device__ __forceinline__ u32x4 ld4cv(const u64* p) {
    u32x4 r;
    asm volatile("global_load_dwordx4 %0, %1, off sc0 sc1" : "=v"(r) : "v"(p));
    return r;
}
__device__ __forceinline__ void stq_bypass(u64* p, u64 v) {
    __hip_atomic_store(p, v, __ATOMIC_RELAXED, __HIP_MEMORY_SCOPE_AGENT);
}
__device__ __forceinline__ int ld_flag(const int* p) {
    return __hip_atomic_load(p, __ATOMIC_RELAXED, __HIP_MEMORY_SCOPE_AGENT);
}
__device__ __forceinline__ int wave_min(int v) {
#pragma unroll
    for (int m = 1; m <= 32; m <<= 1) { int o = __shfl_xor(v, m, 64); v = v < o ? v : o; }
    return v;
}

#define FLAG_STRIDE 16   /* ints -> 64B per flag slot */
#define BIGF (1 << 26)
#define XL_OFF 16384000
#define PS_OFF 16384016

// ws layout (bytes)
#define WS_PROG   0        /* 128 slots x 64B = 8192 */
#define WS_HBUF_F 8192     /* 3 layers x 8 slots x 32KB tagged = 786432 -> 794624 */
#define WS_HBUF_W 794624   /* 8 slots x 16KB tagged = 131072 -> 925696 */
#define WS_REPS   925696   /* 1600x512 fp32 = 3276800 -> 4202496 */
#define WS_RW     4202496  /* 1600x256 bf16 = 819200 -> 5021696 */
#define WS_FPWB   5021696  /* 512x512 bf16 = 524288 -> 5545984 */
#define WS_HSEQ   WS_REPS  /* 1600x256 fp32 overlays reps (reps dead by then) */

// ---------------------------------------------------------------------------
// Persistent 3-layer frame LSTM. 48 WGs (16/layer) x 512 threads.
// WG owns 32 h-cols (128 gate rows, 8 waves x 16-row B tile in registers).
// Cross-WG handoff: tagged u64 h (data u32 + step tag u32) via IF$-bypass;
// consumers poll the data itself. Backward ring guard via progress flags,
// prefetched at step top (off critical path).
// ---------------------------------------------------------------------------
template<int KTIN, bool L0, bool LAST>
__device__ __forceinline__ void frame5(
    const int layer, const int kwg,
    const float* __restrict__ Wih, const float* __restrict__ Whh, const float* __restrict__ bias,
    const float* __restrict__ x, u64* __restrict__ hF, int* __restrict__ prog,
    float* __restrict__ h3out, float* sC, u16* AsIn, u16* AsOwn, u16* sxpad)
{
    const int tid  = threadIdx.x;
    const int lane = tid & 63;
    const int wave = tid >> 6;            // 0..7
    const int n16  = lane & 15;
    const int quad = lane >> 4;
    const int koff = quad * 8;
    const int g = wave >> 1, ch = wave & 1;

    if (L0 && tid < 256) sxpad[(tid >> 4) * 96 + 80 + (tid & 15)] = 0;  // pad cols

    // B fragments: wave handles 16 rows of gate g, col-half ch.
    const int grow = g * 512 + kwg * 32 + ch * 16 + n16;
    short8 bfr[KTIN + 16];
#pragma unroll
    for (int kt = 0; kt < KTIN; ++kt) {
        short8 v = {0,0,0,0,0,0,0,0};
        const int k = kt * 32 + koff;
        if (L0) { if (k + 8 <= 80) v = ld8bf(Wih + grow * 80 + k); }
        else    { v = ld8bf(Wih + (size_t)grow * 512 + k); }
        bfr[kt] = v;
    }
#pragma unroll
    for (int kt = 0; kt < 16; ++kt)
        bfr[KTIN + kt] = ld8bf(Whh + (size_t)grow * 512 + kt * 32 + koff);

    // per-thread gate cell (b, c)
    const int bb = tid >> 5, cc = tid & 31;
    const int col = kwg * 32 + cc;
    const float bI = bias[col], bF = bias[512 + col], bG = bias[1024 + col], bO = bias[1536 + col];
    const int chh = cc >> 4, cl = cc & 15;
    float cs = 0.f;
    int guard = 7;

    const int* flagb = prog + (layer * 16) * FLAG_STRIDE;        // 32 slots: peers + next
    int* myprog = prog + (layer * 16 + kwg) * FLAG_STRIDE;
    u64* const ringO = hF + (size_t)layer * 8 * 4096;
    const u64* const ringI = hF + (size_t)(layer - 1) * 8 * 4096;

    const int xb = tid / 20, xq = tid - xb * 20;
    const float* xp = L0 ? (x + (size_t)xb * 2000 * 80 + xq * 4) : nullptr;
    float* h3p = LAST ? (h3out + (size_t)bb * 2000 * 512 + col) : nullptr;
    __syncthreads();

    for (int t = 0; t < 2000; ++t) {
        // prefetch guard flags (amortized, overlapped with the step)
        const bool chk = (t >= guard);
        int fpre = BIGF;
        if (chk && lane < 32) fpre = ld_flag(flagb + lane * FLAG_STRIDE);
        // L0: x for this step
        float4 xv;
        if (L0) { if (tid < 320) xv = *(const float4*)xp; xp += 80; }
        // poll tagged h (own + in): 4 (+4) dwordx4 per thread, all in flight
        const u64* own = ringO + ((t + 7) & 7) * 4096 + tid * 8;
        const u64* pin = L0 ? nullptr : (ringI + (t & 7) * 4096 + tid * 8);
        u32x4 vow[4], vin[4];
#pragma unroll
        for (int j = 0; j < 4; ++j) vow[j] = ld4cv(own + j * 2);
        if (!L0) {
#pragma unroll
            for (int j = 0; j < 4; ++j) vin[j] = ld4cv(pin + j * 2);
        }
        const u32 tgO = (u32)t, tgI = (u32)(t + 1);
#pragma unroll
        for (int j = 0; j < 4; ++j)
            while (vow[j].y != tgO || vow[j].w != tgO) vow[j] = ld4cv(own + j * 2);
        if (!L0) {
#pragma unroll
            for (int j = 0; j < 4; ++j)
                while (vin[j].y != tgI || vin[j].w != tgI) vin[j] = ld4cv(pin + j * 2);
        }
        // stage to LDS
        if (L0 && tid < 320) {
            u32* d = (u32*)(sxpad + xb * 96 + xq * 4);
            d[0] = pk2(xv.x, xv.y); d[1] = pk2(xv.z, xv.w);
        }
#pragma unroll
        for (int j = 0; j < 4; ++j) {
            const int m = tid * 8 + j * 2;
            const int row = m >> 8, c2 = m & 255;
            *(u64*)((u32*)(AsOwn + row * 520) + c2) = (u64)vow[j].x | ((u64)vow[j].z << 32);
            if (!L0)
                *(u64*)((u32*)(AsIn + row * 520) + c2) = (u64)vin[j].x | ((u64)vin[j].z << 32);
        }
        __syncthreads();
        // gate GEMM
        f32x4 acc[4] = {{0,0,0,0},{0,0,0,0},{0,0,0,0},{0,0,0,0}};
#pragma unroll
        for (int kt = 0; kt < KTIN; ++kt) {
            short8 a = L0 ? *(const short8*)(sxpad + n16 * 96 + kt * 32 + koff)
                          : *(const short8*)(AsIn + n16 * 520 + kt * 32 + koff);
            acc[kt & 3] = mfma16(a, bfr[kt], acc[kt & 3]);
        }
#pragma unroll
        for (int kt = 0; kt < 16; ++kt) {
            short8 a = *(const short8*)(AsOwn + n16 * 520 + kt * 32 + koff);
            acc[(KTIN + kt) & 3] = mfma16(a, bfr[KTIN + kt], acc[(KTIN + kt) & 3]);
        }
        const f32x4 C = acc[0] + acc[1] + acc[2] + acc[3];
#pragma unroll
        for (int r = 0; r < 4; ++r)
            sC[(wave * 16 + quad * 4 + r) * 17 + n16] = C[r];
        __syncthreads();
        // gate math: one h value per thread
        const float gi = sC[((0 + chh) * 16 + bb) * 17 + cl] + bI;
        const float gf = sC[((2 + chh) * 16 + bb) * 17 + cl] + bF;
        const float gg = sC[((4 + chh) * 16 + bb) * 17 + cl] + bG;
        const float go = sC[((6 + chh) * 16 + bb) * 17 + cl] + bO;
        cs = sigm(gf) * cs + sigm(gi) * tanhf(gg);
        const float hn = sigm(go) * tanhf(cs);
        // resolve ring guard before overwriting slot t&7
        if (chk) {
            int f = (lane < 32) ? fpre : BIGF;
            int mn = wave_min(f);
            while (mn < t - 6) {
                __builtin_amdgcn_s_sleep(1);
                f = (lane < 32) ? ld_flag(flagb + lane * FLAG_STRIDE) : BIGF;
                mn = wave_min(f);
            }
            guard = mn + 7;
        }
        // publish tagged h (single store wave, no ack, no flag)
        const float hn1 = __shfl_down(hn, 1);
        if (!(tid & 1))
            stq_bypass(ringO + (t & 7) * 4096 + bb * 256 + kwg * 16 + (cc >> 1),
                       (u64)pk2(hn, hn1) | ((u64)(u32)(t + 1) << 32));
        if (LAST) { *h3p = hn; h3p += 512; }
        if (tid == 0) __hip_atomic_store(myprog, t + 1, __ATOMIC_RELAXED, __HIP_MEMORY_SCOPE_AGENT);
    }
}

__global__ __launch_bounds__(512, 1) void k_frame_lstm5(
    const float* __restrict__ x,
    const float* __restrict__ Wih0, const float* __restrict__ Whh0, const float* __restrict__ b0,
    const float* __restrict__ Wih1, const float* __restrict__ Whh1, const float* __restrict__ b1,
    const float* __restrict__ Wih2, const float* __restrict__ Whh2, const float* __restrict__ b2,
    u64* hF, int* prog, float* h3out)
{
    __shared__ float sC[128 * 17];
    __shared__ __align__(16) u16 AsIn[16 * 520];
    __shared__ __align__(16) u16 AsOwn[16 * 520];
    __shared__ __align__(16) u16 sxpad[16 * 96];
    const int layer = blockIdx.x >> 4;
    const int kwg = blockIdx.x & 15;
    if (layer == 0)      frame5<3,  true,  false>(0, kwg, Wih0, Whh0, b0, x, hF, prog, h3out, sC, AsIn, AsOwn, sxpad);
    else if (layer == 1) frame5<16, false, false>(1, kwg, Wih1, Whh1, b1, x, hF, prog, h3out, sC, AsIn, AsOwn, sxpad);
    else                 frame5<16, false, true >(2, kwg, Wih2, Whh2, b2, x, hF, prog, h3out, sC, AsIn, AsOwn, sxpad);
}

// ---------------------------------------------------------------------------
// Persistent word LSTM: 8 WGs x 512 threads, 100 steps, H=256.
// Same tagged-h scheme; rW read as plain cached loads (prior-kernel data).
// ---------------------------------------------------------------------------
__global__ __launch_bounds__(512, 1) void k_word_lstm5(
    const u16* __restrict__ rW, const float* __restrict__ Wih,
    const float* __restrict__ Whh, const float* __restrict__ bias,
    u64* __restrict__ hW, int* __restrict__ prog, float* __restrict__ hseq)
{
    __shared__ float sC[128 * 17];
    __shared__ __align__(16) u16 AsOwn[16 * 264];
    const int tid = threadIdx.x;
    const int lane = tid & 63;
    const int wave = tid >> 6;
    const int n16 = lane & 15;
    const int quad = lane >> 4;
    const int koff = quad * 8;
    const int g = wave >> 1, ch = wave & 1;
    const int kwg = blockIdx.x;     // 0..7

    const int grow = g * 256 + kwg * 32 + ch * 16 + n16;
    short8 bfr[16];
#pragma unroll
    for (int kt = 0; kt < 8; ++kt) bfr[kt]     = ld8bf(Wih + (size_t)grow * 256 + kt * 32 + koff);
#pragma unroll
    for (int kt = 0; kt < 8; ++kt) bfr[8 + kt] = ld8bf(Whh + (size_t)grow * 256 + kt * 32 + koff);
    const int bb = tid >> 5, cc = tid & 31;
    const int col = kwg * 32 + cc;
    const float bI = bias[col], bF = bias[256 + col], bG = bias[512 + col], bO = bias[768 + col];
    const int chh = cc >> 4, cl = cc & 15;
    float cs = 0.f;
    int guard = 7;
    const int* flagb = prog + 64 * FLAG_STRIDE;   // 8 peers
    int* myprog = prog + (64 + kwg) * FLAG_STRIDE;
    __syncthreads();

    for (int t = 0; t < 100; ++t) {
        const bool chk = (t >= guard);
        int fpre = BIGF;
        if (chk && lane < 8) fpre = ld_flag(flagb + lane * FLAG_STRIDE);
        const u64* own = hW + ((t + 7) & 7) * 2048 + tid * 4;
        u32x4 vow[2];
#pragma unroll
        for (int j = 0; j < 2; ++j) vow[j] = ld4cv(own + j * 2);
        const u32 tgO = (u32)t;
#pragma unroll
        for (int j = 0; j < 2; ++j)
            while (vow[j].y != tgO || vow[j].w != tgO) vow[j] = ld4cv(own + j * 2);
#pragma unroll
        for (int j = 0; j < 2; ++j) {
            const int m = tid * 4 + j * 2;
            const int row = m >> 7, c2 = m & 127;
            *(u64*)((u32*)(AsOwn + row * 264) + c2) = (u64)vow[j].x | ((u64)vow[j].z << 32);
        }
        __syncthreads();
        f32x4 acc[4] = {{0,0,0,0},{0,0,0,0},{0,0,0,0},{0,0,0,0}};
#pragma unroll
        for (int kt = 0; kt < 8; ++kt) {
            short8 a = *(const short8*)(rW + ((size_t)(n16 * 100 + t)) * 256 + kt * 32 + koff);
            acc[kt & 3] = mfma16(a, bfr[kt], acc[kt & 3]);
        }
#pragma unroll
        for (int kt = 0; kt < 8; ++kt) {
            short8 a = *(const short8*)(AsOwn + n16 * 264 + kt * 32 + koff);
            acc[kt & 3] = mfma16(a, bfr[8 + kt], acc[kt & 3]);
        }
        const f32x4 C = acc[0] + acc[1] + acc[2] + acc[3];
#pragma unroll
        for (int r = 0; r < 4; ++r) sC[(wave * 16 + quad * 4 + r) * 17 + n16] = C[r];
        __syncthreads();
        const float gi = sC[((0 + chh) * 16 + bb) * 17 + cl] + bI;
        const float gf = sC[((2 + chh) * 16 + bb) * 17 + cl] + bF;
        const float gg = sC[((4 + chh) * 16 + bb) * 17 + cl] + bG;
        const float go = sC[((6 + chh) * 16 + bb) * 17 + cl] + bO;
        cs = sigm(gf) * cs + sigm(gi) * tanhf(gg);
        const float hn = sigm(go) * tanhf(cs);
        if (chk) {
            int f = (lane < 8) ? fpre : BIGF;
            int mn = wave_min(f);
            while (mn < t - 6) {
                __builtin_amdgcn_s_sleep(1);
                f = (lane < 8) ? ld_flag(flagb + lane * FLAG_STRIDE) : BIGF;
                mn = wave_min(f);
            }
            guard = mn + 7;
        }
        const float hn1 = __shfl_down(hn, 1);
        if (!(tid & 1))
            stq_bypass(hW + (t & 7) * 2048 + bb * 128 + kwg * 16 + (cc >> 1),
                       (u64)pk2(hn, hn1) | ((u64)(u32)(t + 1) << 32));
        hseq[((size_t)(bb * 100 + t)) * 256 + col] = hn;
        if (tid == 0) __hip_atomic_store(myprog, t + 1, __ATOMIC_RELAXED, __HIP_MEMORY_SCOPE_AGENT);
    }
}

// ---------------------------------------------------------------------------
// Ragged tail-mean pooling from fp32 h3 (in d_out): reps fp32 (ws)
// ---------------------------------------------------------------------------
__global__ void k_pool(const float* __restrict__ h3, const int* __restrict__ x_lens,
                       const int* __restrict__ wstarts, const int* __restrict__ wends,
                       const int* __restrict__ wlens, const int* __restrict__ tailp,
                       float* __restrict__ reps)
{
    const int rw = blockIdx.x;
    const int b = rw / 100, w = rw - b * 100;
    const int tid = threadIdx.x;
    const int xl = x_lens[b];
    const int we = wends[rw];
    const int s0 = wstarts[rw];
    const int wl = wlens[b];
    const int tail = tailp[0];
    int ef = we < xl ? we : xl;
    int sf = s0 > 0 ? s0 : 0;
    int i0 = ef - tail; if (i0 < sf) i0 = sf;
    const bool valid = (w < wl) && (we > 0) && (ef > sf) && (ef > i0);
    float a0 = 0.f, a1 = 0.f;
    if (valid) {
        for (int t = i0; t < ef; ++t) {
            const float* hp = h3 + ((size_t)(b * 2000 + t)) * 512;
            a0 += hp[tid];
            a1 += hp[tid + 256];
        }
        const float inv = 1.f / (float)(ef - i0);
        a0 *= inv; a1 *= inv;
    }
    reps[(size_t)rw * 512 + tid] = a0;
    reps[(size_t)rw * 512 + tid + 256] = a1;
}

// ---------------------------------------------------------------------------
// In-place frame projection: y[b,t,:] = mask(h3[b,t,:]) @ fpW^T + fpb (fp32)
// ---------------------------------------------------------------------------
__global__ __launch_bounds__(256, 2) void k_frame_proj(
    float* __restrict__ y, const int* __restrict__ x_lens,
    const u16* __restrict__ fpWb, const float* __restrict__ fpb)
{
    __shared__ __align__(16) u16 As[16 * 520];
    const int tid = threadIdx.x, lane = tid & 63, wave = tid >> 6;
    const int n16 = lane & 15, quad = lane >> 4, koff = quad * 8;
    const int blk = blockIdx.x;          // 2000 blocks: 125 per batch
    const int b = blk / 125;
    const int t0 = (blk - b * 125) * 16;
    const int xl = x_lens[b];
    for (int c = tid; c < 2048; c += 256) {      // 16 rows x 128 float4
        const int row = c >> 7;
        const int q = c & 127;
        const int t = t0 + row;
        float4 v = {0.f, 0.f, 0.f, 0.f};
        if (t < xl) v = *(const float4*)(y + ((size_t)(b * 2000 + t)) * 512 + q * 4);
        u32* d = (u32*)(As + row * 520 + q * 4);
        d[0] = pk2(v.x, v.y);
        d[1] = pk2(v.z, v.w);
    }
    __syncthreads();
    const size_t rowbase = (size_t)b * 2000 + t0;
    for (int ct = 0; ct < 8; ++ct) {
        const int col0 = (wave * 8 + ct) * 16;
        f32x4 acc = {0, 0, 0, 0};
#pragma unroll
        for (int kt = 0; kt < 16; ++kt) {
            short8 a = *(const short8*)(As + n16 * 520 + kt * 32 + koff);
            short8 wv = *(const short8*)(fpWb + ((size_t)(col0 + n16)) * 512 + kt * 32 + koff);
            acc = mfma16(a, wv, acc);
        }
        const float bn = fpb[col0 + n16];
#pragma unroll
        for (int r = 0; r < 4; ++r) {
            const int m = quad * 4 + r;
            y[(rowbase + m) * 512 + col0 + n16] = acc[r] + bn;
        }
    }
}

// ---------------------------------------------------------------------------
// word_proj: Linear(512->256) + LayerNorm + exact GELU per (b,w) row.
// ---------------------------------------------------------------------------
__global__ void k_word_proj(const float* __restrict__ reps, const float* __restrict__ wpW,
                            const float* __restrict__ wpb, const float* __restrict__ lnW,
                            const float* __restrict__ lnB, u16* __restrict__ rW)
{
    __shared__ float sx[512];
    __shared__ float red[512];
    const int tid = threadIdx.x;
    const int row = blockIdx.x;
    for (int k = tid; k < 512; k += 256) sx[k] = reps[(size_t)row * 512 + k];
    __syncthreads();
    float acc = wpb[tid];
    const float4* wr = (const float4*)(wpW + (size_t)tid * 512);
    for (int k4 = 0; k4 < 128; ++k4) {
        const float4 w = wr[k4];
        acc += sx[k4 * 4] * w.x + sx[k4 * 4 + 1] * w.y + sx[k4 * 4 + 2] * w.z + sx[k4 * 4 + 3] * w.w;
    }
    red[tid] = acc; red[256 + tid] = acc * acc;
    __syncthreads();
    for (int s = 128; s > 0; s >>= 1) {
        if (tid < s) { red[tid] += red[tid + s]; red[256 + tid] += red[256 + tid + s]; }
        __syncthreads();
    }
    const float mu = red[0] * (1.f / 256.f);
    float var = red[256] * (1.f / 256.f) - mu * mu;
    if (var < 0.f) var = 0.f;
    const float xn = (acc - mu) * rsqrtf(var + 1e-5f);
    const float yv = xn * lnW[tid] + lnB[tid];
    const float gl = 0.5f * yv * (1.0f + erff(yv * 0.70710678118654752f));
    rW[(size_t)row * 256 + tid] = f2bf(gl);
}

// ---------------------------------------------------------------------------
// pred_sem = mask(hseq) @ spW^T + spb  (fp32 vector math)
// ---------------------------------------------------------------------------
__global__ void k_pred(const float* __restrict__ hseq, const int* __restrict__ wlens,
                       const float* __restrict__ spW, const float* __restrict__ spb,
                       float* __restrict__ out)
{
    __shared__ float sh[256];
    const int tid = threadIdx.x;
    const int rw = blockIdx.x;
    const int b = rw / 100, w = rw - b * 100;
    int wl = wlens[b]; if (wl < 1) wl = 1;
    const bool valid = (w < wl);
    sh[tid] = valid ? hseq[(size_t)rw * 256 + tid] : 0.f;
    __syncthreads();
    for (int o = tid; o < 512; o += 256) {
        float acc = spb[o];
        const float4* wr = (const float4*)(spW + (size_t)o * 256);
        for (int k4 = 0; k4 < 64; ++k4) {
            const float4 wv = wr[k4];
            acc += sh[k4 * 4] * wv.x + sh[k4 * 4 + 1] * wv.y + sh[k4 * 4 + 2] * wv.z + sh[k4 * 4 + 3] * wv.w;
        }
        out[PS_OFF + (size_t)rw * 512 + o] = acc;
    }
}

__global__ void k_xlens(const int* __restrict__ x_lens, float* __restrict__ out)
{
    const int tid = threadIdx.x;
    if (tid < 16) out[XL_OFF + tid] = (float)x_lens[tid];
}

// Pre-cast fpW (512x512 fp32) -> bf16
__global__ void k_cvt(const float* __restrict__ src, u16* __restrict__ dst)
{
    const int e = blockIdx.x * 256 + threadIdx.x;   // 65536 float4s
    const float4 v = *(const float4*)(src + (size_t)e * 4);
    u32* d = (u32*)(dst + (size_t)e * 4);
    d[0] = pk2(v.x, v.y);
    d[1] = pk2(v.z, v.w);
}

// Init prog flags (+sentinels) and zero the tagged h rings, all via bypass
// stores so they're visible to bypass readers. 904 blocks x 256 = 231424 u32
// covers [0, 925696) bytes.
__global__ void k_init5(u32* __restrict__ p)
{
    const int idx = blockIdx.x * 256 + threadIdx.x;
    u32 v = 0u;
    if (idx < 2048) {                       // prog flag area (8 KB)
        const int slot = idx >> 4;
        if (slot >= 48 && slot < 64) v = (u32)BIGF;   // layer-2 "next" sentinels
    }
    __hip_atomic_store(p + idx, v, __ATOMIC_RELAXED, __HIP_MEMORY_SCOPE_AGENT);
}

// ---------------------------------------------------------------------------
extern "C" void kernel_launch(void* const* d_in, const int* in_sizes, int n_in,
                              void* d_out, int out_size, void* d_ws, size_t ws_size,
                              hipStream_t stream)
{
    (void)in_sizes; (void)n_in; (void)out_size; (void)ws_size;
    const float* x    = (const float*)d_in[0];
    const int* x_lens = (const int*)d_in[1];
    const int* wstart = (const int*)d_in[2];
    const int* wend   = (const int*)d_in[3];
    const int* wlen   = (const int*)d_in[4];
    const int* tailp  = (const int*)d_in[5];
    const float* Wih0 = (const float*)d_in[6];
    const float* Whh0 = (const float*)d_in[7];
    const float* b0   = (const float*)d_in[8];
    const float* Wih1 = (const float*)d_in[9];
    const float* Whh1 = (const float*)d_in[10];
    const float* b1   = (const float*)d_in[11];
    const float* Wih2 = (const float*)d_in[12];
    const float* Whh2 = (const float*)d_in[13];
    const float* b2   = (const float*)d_in[14];
    const float* fpW  = (const float*)d_in[15];
    const float* fpb  = (const float*)d_in[16];
    const float* wpW  = (const float*)d_in[17];
    const float* wpb  = (const float*)d_in[18];
    const float* lnW  = (const float*)d_in[19];
    const float* lnB  = (const float*)d_in[20];
    const float* wWih = (const float*)d_in[21];
    const float* wWhh = (const float*)d_in[22];
    const float* wb   = (const float*)d_in[23];
    const float* spW  = (const float*)d_in[24];
    const float* spb  = (const float*)d_in[25];

    float* out = (float*)d_out;
    char* ws = (char*)d_ws;
    int* prog   = (int*)(ws + WS_PROG);
    u64* hbufF  = (u64*)(ws + WS_HBUF_F);
    u64* hbufW  = (u64*)(ws + WS_HBUF_W);
    float* reps = (float*)(ws + WS_REPS);
    u16* rW     = (u16*)(ws + WS_RW);
    float* hseq = (float*)(ws + WS_HSEQ);
    u16* fpWb   = (u16*)(ws + WS_FPWB);

    k_init5<<<904, 256, 0, stream>>>((u32*)d_ws);
    k_cvt<<<256, 256, 0, stream>>>(fpW, fpWb);
    k_frame_lstm5<<<48, 512, 0, stream>>>(x, Wih0, Whh0, b0, Wih1, Whh1, b1,
                                          Wih2, Whh2, b2, hbufF, prog, out);
    k_pool<<<1600, 256, 0, stream>>>(out, x_lens, wstart, wend, wlen, tailp, reps);
    k_frame_proj<<<2000, 256, 0, stream>>>(out, x_lens, fpWb, fpb);  // after k_pool (in-place)
    k_word_proj<<<1600, 256, 0, stream>>>(reps, wpW, wpb, lnW, lnB, rW);
    k_word_lstm5<<<8, 512, 0, stream>>>(rW, wWih, wWhh, wb, hbufW, prog, hseq);
    k_pred<<<1600, 256, 0, stream>>>(hseq, wlen, spW, spb, out);
    k_xlens<<<1, 64, 0, stream>>>(x_lens, out);
}

// Round 7
// 10362.197 us; speedup vs baseline: 1.1965x; 1.1965x over previous
//
#include <hip/hip_runtime.h>
#include <math.h>

typedef unsigned short u16;
typedef unsigned int   u32;
typedef unsigned long long u64;
typedef __attribute__((ext_vector_type(8))) short short8;
typedef __attribute__((ext_vector_type(4))) float f32x4;
typedef __attribute__((ext_vector_type(4))) unsigned int u32x4;

__device__ __forceinline__ float bf2f(u16 v) { return __uint_as_float(((u32)v) << 16); }
__device__ __forceinline__ u16 f2bf(float f) {
    u32 u = __float_as_uint(f);
    u32 r = (u + 0x7fffu + ((u >> 16) & 1u)) >> 16;
    return (u16)r;
}
__device__ __forceinline__ u32 pk2(float a, float b) {
    return ((u32)f2bf(a)) | (((u32)f2bf(b)) << 16);
}
__device__ __forceinline__ float sigm(float x) { return 1.f / (1.f + __expf(-x)); }
__device__ __forceinline__ f32x4 mfma16(short8 a, short8 b, f32x4 c) {
    return __builtin_amdgcn_mfma_f32_16x16x32_bf16(a, b, c, 0, 0, 0);
}
__device__ __forceinline__ short8 ld8bf(const float* p) {
    short8 r;
#pragma unroll
    for (int j = 0; j < 8; ++j) r[j] = (short)f2bf(p[j]);
    return r;
}
// 16B cache-bypassing load (straight from the IF$ coherence point).
// NOTE: result regs are NOT valid until an explicit s_waitcnt vmcnt(0)
// (waitvm below). The compiler cannot see loads inside inline asm, so the
// caller MUST waitvm() between issue and first use / re-issue (WAW hazard).
__device__ __forceinline__ u32x4 ld4cv(const u64* p) {
    u32x4 r;
    asm volatile("global_load_dwordx4 %0, %1, off sc0 sc1" : "=v"(r) : "v"(p));
    return r;
}
__device__ __forceinline__ void stq_bypass(u64* p, u64 v) {
    __hip_atomic_store(p, v, __ATOMIC_RELAXED, __HIP_MEMORY_SCOPE_AGENT);
}
__device__ __forceinline__ int ld_flag(const int* p) {
    return __hip_atomic_load(p, __ATOMIC_RELAXED, __HIP_MEMORY_SCOPE_AGENT);
}
__device__ __forceinline__ void waitvm() {
    asm volatile("s_waitcnt vmcnt(0)" ::: "memory");
}
__device__ __forceinline__ int wave_min(int v) {
#pragma unroll
    for (int m = 1; m <= 32; m <<= 1) { int o = __shfl_xor(v, m, 64); v = v < o ? v : o; }
    return v;
}

#define FLAG_STRIDE 16   /* ints -> 64B per flag slot */
#define BIGF (1 << 26)
#define XL_OFF 16384000
#define PS_OFF 16384016

// ws layout (bytes)
#define WS_PROG   0        /* 128 slots x 64B = 8192 */
#define WS_HBUF_F 8192     /* 3 layers x 8 slots x 32KB tagged = 786432 -> 794624 */
#define WS_HBUF_W 794624   /* 8 slots x 16KB tagged = 131072 -> 925696 */
#define WS_REPS   925696   /* 1600x512 fp32 = 3276800 -> 4202496 */
#define WS_RW     4202496  /* 1600x256 bf16 = 819200 -> 5021696 */
#define WS_FPWB   5021696  /* 512x512 bf16 = 524288 -> 5545984 */
#define WS_HSEQ   WS_REPS  /* 1600x256 fp32 overlays reps (reps dead by then) */

// ---------------------------------------------------------------------------
// Persistent 3-layer frame LSTM. 48 WGs (16/layer) x 512 threads.
// WG owns 32 h-cols (128 gate rows, 8 waves x 16-row B tile in registers).
// Tagged u64 h handoff (data u32 + step tag u32) via IF$-bypass; consumers
// poll the data itself: issue-all -> waitvm -> check-all -> sleep+reissue.
// Backward ring guard via progress flags, prefetched at step top.
// ---------------------------------------------------------------------------
template<int KTIN, bool L0, bool LAST>
__device__ __forceinline__ void frame5(
    const int layer, const int kwg,
    const float* __restrict__ Wih, const float* __restrict__ Whh, const float* __restrict__ bias,
    const float* __restrict__ x, u64* __restrict__ hF, int* __restrict__ prog,
    float* __restrict__ h3out, float* sC, u16* AsIn, u16* AsOwn, u16* sxpad)
{
    const int tid  = threadIdx.x;
    const int lane = tid & 63;
    const int wave = tid >> 6;            // 0..7
    const int n16  = lane & 15;
    const int quad = lane >> 4;
    const int koff = quad * 8;
    const int g = wave >> 1, ch = wave & 1;

    if (L0 && tid < 256) sxpad[(tid >> 4) * 96 + 80 + (tid & 15)] = 0;  // pad cols

    // B fragments: wave handles 16 rows of gate g, col-half ch.
    const int grow = g * 512 + kwg * 32 + ch * 16 + n16;
    short8 bfr[KTIN + 16];
#pragma unroll
    for (int kt = 0; kt < KTIN; ++kt) {
        short8 v = {0,0,0,0,0,0,0,0};
        const int k = kt * 32 + koff;
        if (L0) { if (k + 8 <= 80) v = ld8bf(Wih + grow * 80 + k); }
        else    { v = ld8bf(Wih + (size_t)grow * 512 + k); }
        bfr[kt] = v;
    }
#pragma unroll
    for (int kt = 0; kt < 16; ++kt)
        bfr[KTIN + kt] = ld8bf(Whh + (size_t)grow * 512 + kt * 32 + koff);

    // per-thread gate cell (b, c)
    const int bb = tid >> 5, cc = tid & 31;
    const int col = kwg * 32 + cc;
    const float bI = bias[col], bF = bias[512 + col], bG = bias[1024 + col], bO = bias[1536 + col];
    const int chh = cc >> 4, cl = cc & 15;
    float cs = 0.f;
    int guard = 7;

    const int* flagb = prog + (layer * 16) * FLAG_STRIDE;        // 32 slots: peers + next
    int* myprog = prog + (layer * 16 + kwg) * FLAG_STRIDE;
    u64* const ringO = hF + (size_t)layer * 8 * 4096;
    const u64* const ringI = hF + (size_t)(layer - 1) * 8 * 4096;

    // LDS staging geometry: thread's polled data = contiguous 32B of one row
    const int srow = tid >> 5;
    const int scb = (tid & 31) * 8;      // u32 offset within row

    const int xb = tid / 20, xq = tid - xb * 20;
    const float* xp = (L0 && tid < 320) ? (x + (size_t)xb * 2000 * 80 + xq * 4) : nullptr;
    float* h3p = LAST ? (h3out + (size_t)bb * 2000 * 512 + col) : nullptr;
    __syncthreads();

    for (int t = 0; t < 2000; ++t) {
        // prefetch guard flags (amortized, overlapped with the step)
        const bool chk = (t >= guard);
        int fpre = BIGF;
        if (chk && lane < 32) fpre = ld_flag(flagb + lane * FLAG_STRIDE);
        // L0: x for this step
        float4 xv;
        if (L0) { if (xp) { xv = *(const float4*)xp; xp += 80; } }
        // poll tagged h (own + in): batched issue -> waitvm -> batched check
        const u64* own = ringO + ((t + 7) & 7) * 4096 + tid * 8;
        const u64* pin = L0 ? nullptr : (ringI + (t & 7) * 4096 + tid * 8);
        u32x4 vow[4], vin[4];
        const u32 tgO = (u32)t, tgI = (u32)(t + 1);
#pragma unroll
        for (int j = 0; j < 4; ++j) vow[j] = ld4cv(own + j * 2);
        if (!L0) {
#pragma unroll
            for (int j = 0; j < 4; ++j) vin[j] = ld4cv(pin + j * 2);
        }
        for (;;) {
            waitvm();                       // regs valid only after this
            u32 bad = 0;
#pragma unroll
            for (int j = 0; j < 4; ++j) bad |= (vow[j].y ^ tgO) | (vow[j].w ^ tgO);
            if (!L0) {
#pragma unroll
                for (int j = 0; j < 4; ++j) bad |= (vin[j].y ^ tgI) | (vin[j].w ^ tgI);
            }
            if (!bad) break;
            __builtin_amdgcn_s_sleep(1);
#pragma unroll
            for (int j = 0; j < 4; ++j) vow[j] = ld4cv(own + j * 2);
            if (!L0) {
#pragma unroll
                for (int j = 0; j < 4; ++j) vin[j] = ld4cv(pin + j * 2);
            }
        }
        // stage to LDS (b128 writes: contiguous 32B in-row per thread)
        if (L0 && xp) {
            u32* d = (u32*)(sxpad + xb * 96 + xq * 4);
            d[0] = pk2(xv.x, xv.y); d[1] = pk2(xv.z, xv.w);
        }
        {
            u32* dsto = (u32*)(AsOwn + srow * 520) + scb;
            u32x4 d0 = {vow[0].x, vow[0].z, vow[1].x, vow[1].z};
            u32x4 d1 = {vow[2].x, vow[2].z, vow[3].x, vow[3].z};
            *(u32x4*)(dsto) = d0;
            *(u32x4*)(dsto + 4) = d1;
            if (!L0) {
                u32* dsti = (u32*)(AsIn + srow * 520) + scb;
                u32x4 e0 = {vin[0].x, vin[0].z, vin[1].x, vin[1].z};
                u32x4 e1 = {vin[2].x, vin[2].z, vin[3].x, vin[3].z};
                *(u32x4*)(dsti) = e0;
                *(u32x4*)(dsti + 4) = e1;
            }
        }
        __syncthreads();
        // gate GEMM
        f32x4 acc[4] = {{0,0,0,0},{0,0,0,0},{0,0,0,0},{0,0,0,0}};
#pragma unroll
        for (int kt = 0; kt < KTIN; ++kt) {
            short8 a = L0 ? *(const short8*)(sxpad + n16 * 96 + kt * 32 + koff)
                          : *(const short8*)(AsIn + n16 * 520 + kt * 32 + koff);
            acc[kt & 3] = mfma16(a, bfr[kt], acc[kt & 3]);
        }
#pragma unroll
        for (int kt = 0; kt < 16; ++kt) {
            short8 a = *(const short8*)(AsOwn + n16 * 520 + kt * 32 + koff);
            acc[(KTIN + kt) & 3] = mfma16(a, bfr[KTIN + kt], acc[(KTIN + kt) & 3]);
        }
        const f32x4 C = acc[0] + acc[1] + acc[2] + acc[3];
#pragma unroll
        for (int r = 0; r < 4; ++r)
            sC[(wave * 16 + quad * 4 + r) * 17 + n16] = C[r];
        __syncthreads();
        // gate math: one h value per thread
        const float gi = sC[((0 + chh) * 16 + bb) * 17 + cl] + bI;
        const float gf = sC[((2 + chh) * 16 + bb) * 17 + cl] + bF;
        const float gg = sC[((4 + chh) * 16 + bb) * 17 + cl] + bG;
        const float go = sC[((6 + chh) * 16 + bb) * 17 + cl] + bO;
        cs = sigm(gf) * cs + sigm(gi) * tanhf(gg);
        const float hn = sigm(go) * tanhf(cs);
        // resolve ring guard before overwriting slot t&7
        if (chk) {
            int f = (lane < 32) ? fpre : BIGF;
            int mn = wave_min(f);
            while (mn < t - 6) {
                __builtin_amdgcn_s_sleep(1);
                f = (lane < 32) ? ld_flag(flagb + lane * FLAG_STRIDE) : BIGF;
                mn = wave_min(f);
            }
            guard = mn + 7;
        }
        // publish tagged h (single store wave, no ack, no flag)
        const float hn1 = __shfl_down(hn, 1);
        if (!(tid & 1))
            stq_bypass(ringO + (t & 7) * 4096 + bb * 256 + kwg * 16 + (cc >> 1),
                       (u64)pk2(hn, hn1) | ((u64)(u32)(t + 1) << 32));
        if (LAST) { *h3p = hn; h3p += 512; }
        if (tid == 0) __hip_atomic_store(myprog, t + 1, __ATOMIC_RELAXED, __HIP_MEMORY_SCOPE_AGENT);
    }
}

__global__ __launch_bounds__(512, 1) void k_frame_lstm5(
    const float* __restrict__ x,
    const float* __restrict__ Wih0, const float* __restrict__ Whh0, const float* __restrict__ b0,
    const float* __restrict__ Wih1, const float* __restrict__ Whh1, const float* __restrict__ b1,
    const float* __restrict__ Wih2, const float* __restrict__ Whh2, const float* __restrict__ b2,
    u64* hF, int* prog, float* h3out)
{
    __shared__ float sC[128 * 17];
    __shared__ __align__(16) u16 AsIn[16 * 520];
    __shared__ __align__(16) u16 AsOwn[16 * 520];
    __shared__ __align__(16) u16 sxpad[16 * 96];
    const int layer = blockIdx.x >> 4;
    const int kwg = blockIdx.x & 15;
    if (layer == 0)      frame5<3,  true,  false>(0, kwg, Wih0, Whh0, b0, x, hF, prog, h3out, sC, AsIn, AsOwn, sxpad);
    else if (layer == 1) frame5<16, false, false>(1, kwg, Wih1, Whh1, b1, x, hF, prog, h3out, sC, AsIn, AsOwn, sxpad);
    else                 frame5<16, false, true >(2, kwg, Wih2, Whh2, b2, x, hF, prog, h3out, sC, AsIn, AsOwn, sxpad);
}

// ---------------------------------------------------------------------------
// Persistent word LSTM: 8 WGs x 512 threads, 100 steps, H=256.
// Same tagged-h scheme (issue -> waitvm -> check); rW via plain cached loads.
// ---------------------------------------------------------------------------
__global__ __launch_bounds__(512, 1) void k_word_lstm5(
    const u16* __restrict__ rW, const float* __restrict__ Wih,
    const float* __restrict__ Whh, const float* __restrict__ bias,
    u64* __restrict__ hW, int* __restrict__ prog, float* __restrict__ hseq)
{
    __shared__ float sC[128 * 17];
    __shared__ __align__(16) u16 AsOwn[16 * 264];
    const int tid = threadIdx.x;
    const int lane = tid & 63;
    const int wave = tid >> 6;
    const int n16 = lane & 15;
    const int quad = lane >> 4;
    const int koff = quad * 8;
    const int g = wave >> 1, ch = wave & 1;
    const int kwg = blockIdx.x;     // 0..7

    const int grow = g * 256 + kwg * 32 + ch * 16 + n16;
    short8 bfr[16];
#pragma unroll
    for (int kt = 0; kt < 8; ++kt) bfr[kt]     = ld8bf(Wih + (size_t)grow * 256 + kt * 32 + koff);
#pragma unroll
    for (int kt = 0; kt < 8; ++kt) bfr[8 + kt] = ld8bf(Whh + (size_t)grow * 256 + kt * 32 + koff);
    const int bb = tid >> 5, cc = tid & 31;
    const int col = kwg * 32 + cc;
    const float bI = bias[col], bF = bias[256 + col], bG = bias[512 + col], bO = bias[768 + col];
    const int chh = cc >> 4, cl = cc & 15;
    float cs = 0.f;
    int guard = 7;
    const int* flagb = prog + 64 * FLAG_STRIDE;   // 8 peers
    int* myprog = prog + (64 + kwg) * FLAG_STRIDE;
    const int srow = tid >> 5;
    const int scb = (tid & 31) * 4;      // u32 offset within row (128 u32/row)
    __syncthreads();

    for (int t = 0; t < 100; ++t) {
        const bool chk = (t >= guard);
        int fpre = BIGF;
        if (chk && lane < 8) fpre = ld_flag(flagb + lane * FLAG_STRIDE);
        const u64* own = hW + ((t + 7) & 7) * 2048 + tid * 4;
        u32x4 vow[2];
        const u32 tgO = (u32)t;
#pragma unroll
        for (int j = 0; j < 2; ++j) vow[j] = ld4cv(own + j * 2);
        for (;;) {
            waitvm();
            u32 bad = 0;
#pragma unroll
            for (int j = 0; j < 2; ++j) bad |= (vow[j].y ^ tgO) | (vow[j].w ^ tgO);
            if (!bad) break;
            __builtin_amdgcn_s_sleep(1);
#pragma unroll
            for (int j = 0; j < 2; ++j) vow[j] = ld4cv(own + j * 2);
        }
        {
            u32* dst = (u32*)(AsOwn + srow * 264) + scb;
            u32x4 d0 = {vow[0].x, vow[0].z, vow[1].x, vow[1].z};
            *(u32x4*)dst = d0;
        }
        __syncthreads();
        f32x4 acc[4] = {{0,0,0,0},{0,0,0,0},{0,0,0,0},{0,0,0,0}};
#pragma unroll
        for (int kt = 0; kt < 8; ++kt) {
            short8 a = *(const short8*)(rW + ((size_t)(n16 * 100 + t)) * 256 + kt * 32 + koff);
            acc[kt & 3] = mfma16(a, bfr[kt], acc[kt & 3]);
        }
#pragma unroll
        for (int kt = 0; kt < 8; ++kt) {
            short8 a = *(const short8*)(AsOwn + n16 * 264 + kt * 32 + koff);
            acc[kt & 3] = mfma16(a, bfr[8 + kt], acc[kt & 3]);
        }
        const f32x4 C = acc[0] + acc[1] + acc[2] + acc[3];
#pragma unroll
        for (int r = 0; r < 4; ++r) sC[(wave * 16 + quad * 4 + r) * 17 + n16] = C[r];
        __syncthreads();
        const float gi = sC[((0 + chh) * 16 + bb) * 17 + cl] + bI;
        const float gf = sC[((2 + chh) * 16 + bb) * 17 + cl] + bF;
        const float gg = sC[((4 + chh) * 16 + bb) * 17 + cl] + bG;
        const float go = sC[((6 + chh) * 16 + bb) * 17 + cl] + bO;
        cs = sigm(gf) * cs + sigm(gi) * tanhf(gg);
        const float hn = sigm(go) * tanhf(cs);
        if (chk) {
            int f = (lane < 8) ? fpre : BIGF;
            int mn = wave_min(f);
            while (mn < t - 6) {
                __builtin_amdgcn_s_sleep(1);
                f = (lane < 8) ? ld_flag(flagb + lane * FLAG_STRIDE) : BIGF;
                mn = wave_min(f);
            }
            guard = mn + 7;
        }
        const float hn1 = __shfl_down(hn, 1);
        if (!(tid & 1))
            stq_bypass(hW + (t & 7) * 2048 + bb * 128 + kwg * 16 + (cc >> 1),
                       (u64)pk2(hn, hn1) | ((u64)(u32)(t + 1) << 32));
        hseq[((size_t)(bb * 100 + t)) * 256 + col] = hn;
        if (tid == 0) __hip_atomic_store(myprog, t + 1, __ATOMIC_RELAXED, __HIP_MEMORY_SCOPE_AGENT);
    }
}

// ---------------------------------------------------------------------------
// Ragged tail-mean pooling from fp32 h3 (in d_out): reps fp32 (ws)
// ---------------------------------------------------------------------------
__global__ void k_pool(const float* __restrict__ h3, const int* __restrict__ x_lens,
                       const int* __restrict__ wstarts, const int* __restrict__ wends,
                       const int* __restrict__ wlens, const int* __restrict__ tailp,
                       float* __restrict__ reps)
{
    const int rw = blockIdx.x;
    const int b = rw / 100, w = rw - b * 100;
    const int tid = threadIdx.x;
    const int xl = x_lens[b];
    const int we = wends[rw];
    const int s0 = wstarts[rw];
    const int wl = wlens[b];
    const int tail = tailp[0];
    int ef = we < xl ? we : xl;
    int sf = s0 > 0 ? s0 : 0;
    int i0 = ef - tail; if (i0 < sf) i0 = sf;
    const bool valid = (w < wl) && (we > 0) && (ef > sf) && (ef > i0);
    float a0 = 0.f, a1 = 0.f;
    if (valid) {
        for (int t = i0; t < ef; ++t) {
            const float* hp = h3 + ((size_t)(b * 2000 + t)) * 512;
            a0 += hp[tid];
            a1 += hp[tid + 256];
        }
        const float inv = 1.f / (float)(ef - i0);
        a0 *= inv; a1 *= inv;
    }
    reps[(size_t)rw * 512 + tid] = a0;
    reps[(size_t)rw * 512 + tid + 256] = a1;
}

// ---------------------------------------------------------------------------
// In-place frame projection: y[b,t,:] = mask(h3[b,t,:]) @ fpW^T + fpb (fp32)
// ---------------------------------------------------------------------------
__global__ __launch_bounds__(256, 2) void k_frame_proj(
    float* __restrict__ y, const int* __restrict__ x_lens,
    const u16* __restrict__ fpWb, const float* __restrict__ fpb)
{
    __shared__ __align__(16) u16 As[16 * 520];
    const int tid = threadIdx.x, lane = tid & 63, wave = tid >> 6;
    const int n16 = lane & 15, quad = lane >> 4, koff = quad * 8;
    const int blk = blockIdx.x;          // 2000 blocks: 125 per batch
    const int b = blk / 125;
    const int t0 = (blk - b * 125) * 16;
    const int xl = x_lens[b];
    for (int c = tid; c < 2048; c += 256) {      // 16 rows x 128 float4
        const int row = c >> 7;
        const int q = c & 127;
        const int t = t0 + row;
        float4 v = {0.f, 0.f, 0.f, 0.f};
        if (t < xl) v = *(const float4*)(y + ((size_t)(b * 2000 + t)) * 512 + q * 4);
        u32* d = (u32*)(As + row * 520 + q * 4);
        d[0] = pk2(v.x, v.y);
        d[1] = pk2(v.z, v.w);
    }
    __syncthreads();
    const size_t rowbase = (size_t)b * 2000 + t0;
    for (int ct = 0; ct < 8; ++ct) {
        const int col0 = (wave * 8 + ct) * 16;
        f32x4 acc = {0, 0, 0, 0};
#pragma unroll
        for (int kt = 0; kt < 16; ++kt) {
            short8 a = *(const short8*)(As + n16 * 520 + kt * 32 + koff);
            short8 wv = *(const short8*)(fpWb + ((size_t)(col0 + n16)) * 512 + kt * 32 + koff);
            acc = mfma16(a, wv, acc);
        }
        const float bn = fpb[col0 + n16];
#pragma unroll
        for (int r = 0; r < 4; ++r) {
            const int m = quad * 4 + r;
            y[(rowbase + m) * 512 + col0 + n16] = acc[r] + bn;
        }
    }
}

// ---------------------------------------------------------------------------
// word_proj: Linear(512->256) + LayerNorm + exact GELU per (b,w) row.
// ---------------------------------------------------------------------------
__global__ void k_word_proj(const float* __restrict__ reps, const float* __restrict__ wpW,
                            const float* __restrict__ wpb, const float* __restrict__ lnW,
                            const float* __restrict__ lnB, u16* __restrict__ rW)
{
    __shared__ float sx[512];
    __shared__ float red[512];
    const int tid = threadIdx.x;
    const int row = blockIdx.x;
    for (int k = tid; k < 512; k += 256) sx[k] = reps[(size_t)row * 512 + k];
    __syncthreads();
    float acc = wpb[tid];
    const float4* wr = (const float4*)(wpW + (size_t)tid * 512);
    for (int k4 = 0; k4 < 128; ++k4) {
        const float4 w = wr[k4];
        acc += sx[k4 * 4] * w.x + sx[k4 * 4 + 1] * w.y + sx[k4 * 4 + 2] * w.z + sx[k4 * 4 + 3] * w.w;
    }
    red[tid] = acc; red[256 + tid] = acc * acc;
    __syncthreads();
    for (int s = 128; s > 0; s >>= 1) {
        if (tid < s) { red[tid] += red[tid + s]; red[256 + tid] += red[256 + tid + s]; }
        __syncthreads();
    }
    const float mu = red[0] * (1.f / 256.f);
    float var = red[256] * (1.f / 256.f) - mu * mu;
    if (var < 0.f) var = 0.f;
    const float xn = (acc - mu) * rsqrtf(var + 1e-5f);
    const float yv = xn * lnW[tid] + lnB[tid];
    const float gl = 0.5f * yv * (1.0f + erff(yv * 0.70710678118654752f));
    rW[(size_t)row * 256 + tid] = f2bf(gl);
}

// ---------------------------------------------------------------------------
// pred_sem = mask(hseq) @ spW^T + spb  (fp32 vector math)
// ---------------------------------------------------------------------------
__global__ void k_pred(const float* __restrict__ hseq, const int* __restrict__ wlens,
                       const float* __restrict__ spW, const float* __restrict__ spb,
                       float* __restrict__ out)
{
    __shared__ float sh[256];
    const int tid = threadIdx.x;
    const int rw = blockIdx.x;
    const int b = rw / 100, w = rw - b * 100;
    int wl = wlens[b]; if (wl < 1) wl = 1;
    const bool valid = (w < wl);
    sh[tid] = valid ? hseq[(size_t)rw * 256 + tid] : 0.f;
    __syncthreads();
    for (int o = tid; o < 512; o += 256) {
        float acc = spb[o];
        const float4* wr = (const float4*)(spW + (size_t)o * 256);
        for (int k4 = 0; k4 < 64; ++k4) {
            const float4 wv = wr[k4];
            acc += sh[k4 * 4] * wv.x + sh[k4 * 4 + 1] * wv.y + sh[k4 * 4 + 2] * wv.z + sh[k4 * 4 + 3] * wv.w;
        }
        out[PS_OFF + (size_t)rw * 512 + o] = acc;
    }
}

__global__ void k_xlens(const int* __restrict__ x_lens, float* __restrict__ out)
{
    const int tid = threadIdx.x;
    if (tid < 16) out[XL_OFF + tid] = (float)x_lens[tid];
}

// Pre-cast fpW (512x512 fp32) -> bf16
__global__ void k_cvt(const float* __restrict__ src, u16* __restrict__ dst)
{
    const int e = blockIdx.x * 256 + threadIdx.x;   // 65536 float4s
    const float4 v = *(const float4*)(src + (size_t)e * 4);
    u32* d = (u32*)(dst + (size_t)e * 4);
    d[0] = pk2(v.x, v.y);
    d[1] = pk2(v.z, v.w);
}

// Init prog flags (+sentinels) and zero the tagged h rings via bypass stores.
// 904 blocks x 256 = 231424 u32 covers [0, 925696) bytes.
__global__ void k_init5(u32* __restrict__ p)
{
    const int idx = blockIdx.x * 256 + threadIdx.x;
    u32 v = 0u;
    if (idx < 2048) {                       // prog flag area (8 KB)
        const int slot = idx >> 4;
        if (slot >= 48 && slot < 64) v = (u32)BIGF;   // layer-2 "next" sentinels
    }
    __hip_atomic_store(p + idx, v, __ATOMIC_RELAXED, __HIP_MEMORY_SCOPE_AGENT);
}

// ---------------------------------------------------------------------------
extern "C" void kernel_launch(void* const* d_in, const int* in_sizes, int n_in,
                              void* d_out, int out_size, void* d_ws, size_t ws_size,
                              hipStream_t stream)
{
    (void)in_sizes; (void)n_in; (void)out_size; (void)ws_size;
    const float* x    = (const float*)d_in[0];
    const int* x_lens = (const int*)d_in[1];
    const int* wstart = (const int*)d_in[2];
    const int* wend   = (const int*)d_in[3];
    const int* wlen   = (const int*)d_in[4];
    const int* tailp  = (const int*)d_in[5];
    const float* Wih0 = (const float*)d_in[6];
    const float* Whh0 = (const float*)d_in[7];
    const float* b0   = (const float*)d_in[8];
    const float* Wih1 = (const float*)d_in[9];
    const float* Whh1 = (const float*)d_in[10];
    const float* b1   = (const float*)d_in[11];
    const float* Wih2 = (const float*)d_in[12];
    const float* Whh2 = (const float*)d_in[13];
    const float* b2   = (const float*)d_in[14];
    const float* fpW  = (const float*)d_in[15];
    const float* fpb  = (const float*)d_in[16];
    const float* wpW  = (const float*)d_in[17];
    const float* wpb  = (const float*)d_in[18];
    const float* lnW  = (const float*)d_in[19];
    const float* lnB  = (const float*)d_in[20];
    const float* wWih = (const float*)d_in[21];
    const float* wWhh = (const float*)d_in[22];
    const float* wb   = (const float*)d_in[23];
    const float* spW  = (const float*)d_in[24];
    const float* spb  = (const float*)d_in[25];

    float* out = (float*)d_out;
    char* ws = (char*)d_ws;
    int* prog   = (int*)(ws + WS_PROG);
    u64* hbufF  = (u64*)(ws + WS_HBUF_F);
    u64* hbufW  = (u64*)(ws + WS_HBUF_W);
    float* reps = (float*)(ws + WS_REPS);
    u16* rW     = (u16*)(ws + WS_RW);
    float* hseq = (float*)(ws + WS_HSEQ);
    u16* fpWb   = (u16*)(ws + WS_FPWB);

    k_init5<<<904, 256, 0, stream>>>((u32*)d_ws);
    k_cvt<<<256, 256, 0, stream>>>(fpW, fpWb);
    k_frame_lstm5<<<48, 512, 0, stream>>>(x, Wih0, Whh0, b0, Wih1, Whh1, b1,
                                          Wih2, Whh2, b2, hbufF, prog, out);
    k_pool<<<1600, 256, 0, stream>>>(out, x_lens, wstart, wend, wlen, tailp, reps);
    k_frame_proj<<<2000, 256, 0, stream>>>(out, x_lens, fpWb, fpb);  // after k_pool (in-place)
    k_word_proj<<<1600, 256, 0, stream>>>(reps, wpW, wpb, lnW, lnB, rW);
    k_word_lstm5<<<8, 512, 0, stream>>>(rW, wWih, wWhh, wb, hbufW, prog, hseq);
    k_pred<<<1600, 256, 0, stream>>>(hseq, wlen, spW, spb, out);
    k_xlens<<<1, 64, 0, stream>>>(x_lens, out);
}